// Round 1
// baseline (8164.771 us; speedup 1.0000x reference)
//
#include <hip/hip_runtime.h>

// VectorQuantizer: fused distance-GEMM + argmin + gather + losses.
// N=32768 rows (8*64*64), D=256, K=8192 codes.
// d[n,k] = fl(fl(a_n - 2*u_nk) + c_k) replicated exactly in f32 (argmin
// ties broken to lowest k, matching np/jnp first-occurrence argmin).

#define NROWS 32768
#define NE    8192
#define DDIM  256
#define BM    128
#define BN    128
#define BK    32
#define NSTEPS (64 * 8)   // 64 candidate chunks * 8 k-tiles

// ---------------- row-norm precompute: a[n] = sum z^2, c[k] = sum e^2 ----
__global__ __launch_bounds__(256)
void vq_norms(const float* __restrict__ z, const float* __restrict__ emb,
              float* __restrict__ arow, float* __restrict__ cemb) {
  int gid  = blockIdx.x * 256 + threadIdx.x;
  int wid  = gid >> 6;          // one wave per row
  int lane = threadIdx.x & 63;
  const float* src;
  float* dst;
  if (wid < NROWS) { src = z + (size_t)wid * DDIM;            dst = arow + wid; }
  else             { int r = wid - NROWS;
                     src = emb + (size_t)r * DDIM;            dst = cemb + r; }
  float4 v = *reinterpret_cast<const float4*>(src + lane * 4);
  float s = v.x * v.x + v.y * v.y;
  s += v.z * v.z;
  s += v.w * v.w;
  #pragma unroll
  for (int off = 1; off < 64; off <<= 1) s += __shfl_xor(s, off, 64);
  if (lane == 0) *dst = s;
}

// ---------------- main fused kernel ------------------------------------
__global__ __launch_bounds__(256)
void vq_main(const float* __restrict__ z, const float* __restrict__ emb,
             const float* __restrict__ arow, const float* __restrict__ cemb,
             float* __restrict__ out_zq, float* __restrict__ out_idx,
             double* __restrict__ loss_accum) {
  // k-major LDS tiles, XOR-swizzled columns (sw = ((k>>2)&3)<<3) to break
  // the 8-way staging-write conflict while keeping b128 reads aligned.
  __shared__ float zs[2][BK][BM];
  __shared__ float es[2][BK][BN];

  const int t  = threadIdx.x;
  const int tx = t & 15;           // candidate-thread
  const int ty = t >> 4;           // row-thread
  const int r0 = ty * 8;
  const int c0 = tx * 8;
  const int R0 = blockIdx.x * BM;

  float a_r[8];
  #pragma unroll
  for (int i = 0; i < 8; ++i) a_r[i] = arow[R0 + r0 + i];

  float acc[8][8];
  float bd[8];
  int   bki[8];
  #pragma unroll
  for (int i = 0; i < 8; ++i) { bd[i] = 3.4e38f; bki[i] = 0; }

  float4 ld[8];   // staging registers (async-split: load early, write late)

  auto stage_load = [&](int s) {
    const int ch = s >> 3, kt = s & 7;
    const int kbase = kt * BK;
    const int C0 = ch * BN;
    #pragma unroll
    for (int i = 0; i < 4; ++i) {
      int l = i * 256 + t;
      int r = l >> 3, q = l & 7;
      ld[i] = *reinterpret_cast<const float4*>(
          z + (size_t)(R0 + r) * DDIM + kbase + q * 4);
    }
    #pragma unroll
    for (int i = 0; i < 4; ++i) {
      int l = i * 256 + t;
      int r = l >> 3, q = l & 7;
      ld[4 + i] = *reinterpret_cast<const float4*>(
          emb + (size_t)(C0 + r) * DDIM + kbase + q * 4);
    }
  };

  auto stage_write = [&](int buf) {
    #pragma unroll
    for (int i = 0; i < 4; ++i) {
      int l = i * 256 + t;
      int r = l >> 3, q = l & 7;
      int col = r ^ ((q & 3) << 3);
      zs[buf][q * 4 + 0][col] = ld[i].x;
      zs[buf][q * 4 + 1][col] = ld[i].y;
      zs[buf][q * 4 + 2][col] = ld[i].z;
      zs[buf][q * 4 + 3][col] = ld[i].w;
    }
    #pragma unroll
    for (int i = 0; i < 4; ++i) {
      int l = i * 256 + t;
      int r = l >> 3, q = l & 7;
      int col = r ^ ((q & 3) << 3);
      es[buf][q * 4 + 0][col] = ld[4 + i].x;
      es[buf][q * 4 + 1][col] = ld[4 + i].y;
      es[buf][q * 4 + 2][col] = ld[4 + i].z;
      es[buf][q * 4 + 3][col] = ld[4 + i].w;
    }
  };

  auto compute = [&](int buf) {
    #pragma unroll
    for (int kk = 0; kk < BK; ++kk) {
      const int sw = ((kk >> 2) & 3) << 3;   // unroll-time constant
      const float4 z0 = *reinterpret_cast<const float4*>(&zs[buf][kk][r0 ^ sw]);
      const float4 z1 = *reinterpret_cast<const float4*>(&zs[buf][kk][(r0 ^ sw) + 4]);
      const float4 e0 = *reinterpret_cast<const float4*>(&es[buf][kk][c0 ^ sw]);
      const float4 e1 = *reinterpret_cast<const float4*>(&es[buf][kk][(c0 ^ sw) + 4]);
      const float zr[8] = {z0.x, z0.y, z0.z, z0.w, z1.x, z1.y, z1.z, z1.w};
      const float ec[8] = {e0.x, e0.y, e0.z, e0.w, e1.x, e1.y, e1.z, e1.w};
      #pragma unroll
      for (int i = 0; i < 8; ++i)
        #pragma unroll
        for (int j = 0; j < 8; ++j)
          acc[i][j] = fmaf(zr[i], ec[j], acc[i][j]);
    }
  };

  stage_load(0);
  stage_write(0);
  __syncthreads();

  int buf = 0;
  for (int s = 0; s < NSTEPS; ++s) {
    const int kt = s & 7;
    if (kt == 0) {
      #pragma unroll
      for (int i = 0; i < 8; ++i)
        #pragma unroll
        for (int j = 0; j < 8; ++j) acc[i][j] = 0.0f;
    }
    const bool more = (s + 1 < NSTEPS);
    if (more) stage_load(s + 1);   // issue global loads before the FMA block
    compute(buf);
    if (more) stage_write(buf ^ 1);  // latency long hidden; write other buffer
    if (kt == 7) {
      const int ch = s >> 3;
      const int C0 = ch * BN;
      const float4 cc0 = *reinterpret_cast<const float4*>(cemb + C0 + c0);
      const float4 cc1 = *reinterpret_cast<const float4*>(cemb + C0 + c0 + 4);
      const float cv[8] = {cc0.x, cc0.y, cc0.z, cc0.w,
                           cc1.x, cc1.y, cc1.z, cc1.w};
      #pragma unroll
      for (int i = 0; i < 8; ++i) {
        #pragma unroll
        for (int j = 0; j < 8; ++j) {
          // exact ref chain: fl(a - 2u) (2u exact -> fma-safe) then + c
          float t1 = a_r[i] - 2.0f * acc[i][j];
          float d  = t1 + cv[j];
          // strict < keeps first (lowest-k) minimum; k ascends over s,j
          if (d < bd[i]) { bd[i] = d; bki[i] = C0 + c0 + j; }
        }
      }
    }
    __syncthreads();
    buf ^= 1;
  }

  // cross-lane argmin over the 16 tx lanes (consecutive within a wave),
  // lexicographic (d, k) so ties resolve to the lowest index.
  int* bkShared = reinterpret_cast<int*>(&zs[0][0][0]);
  #pragma unroll
  for (int i = 0; i < 8; ++i) {
    float d = bd[i];
    int   k = bki[i];
    #pragma unroll
    for (int off = 1; off < 16; off <<= 1) {
      float od = __shfl_xor(d, off, 64);
      int   ok = __shfl_xor(k, off, 64);
      if (od < d || (od == d && ok < k)) { d = od; k = ok; }
    }
    if (tx == 0) bkShared[r0 + i] = k;
  }
  __syncthreads();

  // gather + z_q_ste write + loss accumulation (one row per iteration,
  // 256 threads = 256 cols, fully coalesced; emb rows are L2/L3-hot)
  float lsum = 0.0f;
  for (int rr = 0; rr < BM; ++rr) {
    const int kb = bkShared[rr];
    const size_t gi = (size_t)(R0 + rr) * DDIM + t;
    const float zv = z[gi];
    const float qv = emb[(size_t)kb * DDIM + t];
    const float diff = qv - zv;            // z_q - z
    out_zq[gi] = zv + diff;                // z + (z_q - z), exact ref chain
    lsum = fmaf(diff, diff, lsum);
  }
  #pragma unroll
  for (int off = 1; off < 64; off <<= 1) lsum += __shfl_xor(lsum, off, 64);
  float* part = reinterpret_cast<float*>(&es[0][0][0]);
  if ((t & 63) == 0) part[t >> 6] = lsum;
  __syncthreads();
  if (t == 0) {
    float tot = (part[0] + part[1]) + (part[2] + part[3]);
    atomicAdd(loss_accum, (double)tot);
  }
  if (t < BM) out_idx[R0 + t] = (float)bkShared[t];
}

// ---------------- scalar losses ----------------------------------------
__global__ void vq_finalize(const double* __restrict__ loss_accum,
                            float* __restrict__ out_losses) {
  double m = *loss_accum / (double)(NROWS * DDIM);
  out_losses[0] = (float)(0.25 * m);   // loss_commit = BETA * mse
  out_losses[1] = (float)m;            // loss_codebook = mse
}

extern "C" void kernel_launch(void* const* d_in, const int* in_sizes, int n_in,
                              void* d_out, int out_size, void* d_ws, size_t ws_size,
                              hipStream_t stream) {
  const float* z   = (const float*)d_in[0];
  const float* emb = (const float*)d_in[1];
  float* out        = (float*)d_out;
  float* out_zq     = out;                       // [8388608]
  float* out_losses = out + (size_t)NROWS * DDIM; // [2]
  float* out_idx    = out + (size_t)NROWS * DDIM + 2; // [32768] as f32

  double* loss_accum = (double*)d_ws;
  float*  arow = (float*)((char*)d_ws + 256);
  float*  cemb = arow + NROWS;

  hipMemsetAsync(d_ws, 0, 8, stream);           // zero loss accumulator
  vq_norms<<<(NROWS + NE) / 4, 256, 0, stream>>>(z, emb, arow, cemb);
  vq_main<<<NROWS / BM, 256, 0, stream>>>(z, emb, arow, cemb,
                                          out_zq, out_idx, loss_accum);
  vq_finalize<<<1, 1, 0, stream>>>(loss_accum, out_losses);
}

// Round 2
// 2846.208 us; speedup vs baseline: 2.8686x; 2.8686x over previous
//
#include <hip/hip_runtime.h>

// VectorQuantizer: fused distance-GEMM + argmin + gather + losses.
// N=32768 rows (8*64*64), D=256, K=8192 codes.
// d[n,k] = fl(fl(a_n - 2*u_nk) + c_k) replicated exactly in f32 (argmin
// ties broken to lowest k, matching np first-occurrence argmin).
//
// Round 2: kill register spills (R1: VGPR=256, 18.8GB scratch writes).
//  - global_load_lds (16B) staging: no staging VGPRs, no stage-write VALU.
//  - row-major LDS tiles [128][32], linear dest as required by the DMA;
//    bank conflicts broken by pre-swizzling the GLOBAL source column
//    (LDS[r][q] holds global chunk q ^ ((r>>3)&7)), same XOR on read.

#define NROWS 32768
#define NE    8192
#define DDIM  256
#define BM    128
#define BN    128
#define BK    32
#define NCHUNK (NE / BN)        // 64
#define NKT    (DDIM / BK)      // 8
#define NSTEPS (NCHUNK * NKT)   // 512

__device__ __forceinline__ void gload_lds16(const float* g, float* l) {
  __builtin_amdgcn_global_load_lds(
      (const __attribute__((address_space(1))) void*)g,
      (__attribute__((address_space(3))) void*)l, 16, 0, 0);
}

// ---------------- row-norm precompute: a[n] = sum z^2, c[k] = sum e^2 ----
__global__ __launch_bounds__(256)
void vq_norms(const float* __restrict__ z, const float* __restrict__ emb,
              float* __restrict__ arow, float* __restrict__ cemb) {
  int gid  = blockIdx.x * 256 + threadIdx.x;
  int wid  = gid >> 6;          // one wave per row
  int lane = threadIdx.x & 63;
  const float* src;
  float* dst;
  if (wid < NROWS) { src = z + (size_t)wid * DDIM;            dst = arow + wid; }
  else             { int r = wid - NROWS;
                     src = emb + (size_t)r * DDIM;            dst = cemb + r; }
  float4 v = *reinterpret_cast<const float4*>(src + lane * 4);
  float s = v.x * v.x + v.y * v.y;
  s += v.z * v.z;
  s += v.w * v.w;
  #pragma unroll
  for (int off = 1; off < 64; off <<= 1) s += __shfl_xor(s, off, 64);
  if (lane == 0) *dst = s;
}

// ---------------- main fused kernel ------------------------------------
__global__ __launch_bounds__(256)
void vq_main(const float* __restrict__ z, const float* __restrict__ emb,
             const float* __restrict__ arow, const float* __restrict__ cemb,
             float* __restrict__ out_zq, float* __restrict__ out_idx,
             double* __restrict__ loss_accum) {
  __shared__ float zs[2][BM][BK];   // 2 x 16 KB
  __shared__ float es[2][BN][BK];   // 2 x 16 KB   (total 64 KB -> 2 blk/CU)

  const int t   = threadIdx.x;
  const int tx  = t & 15;           // candidate-thread
  const int ty  = t >> 4;           // row-thread
  const int r0  = ty * 8;
  const int c0  = tx * 8;
  const int R0  = blockIdx.x * BM;
  const int wid = t >> 6;
  const int tyx = ty & 7;           // z-read swizzle key ((row>>3)&7 for r0..r0+7)
  const int txx = tx & 7;           // e-read swizzle key

  // ---- staging constants (per-lane, loop-invariant) ----
  // call i covers LDS floats [(i*256+t)*4, +4): row = i*32 + (t>>3), pos q = t&7.
  // source column chunk is pre-swizzled: qg = q ^ ((row>>3)&7).
  const int rsub = t >> 3;          // 0..31
  const int qpos = t & 7;
  const float* zsrc[4];
  const float* esrc[4];
  #pragma unroll
  for (int i = 0; i < 4; ++i) {
    const int row = i * 32 + rsub;
    const int qg  = qpos ^ ((row >> 3) & 7);
    zsrc[i] = z   + (size_t)(R0 + row) * DDIM + qg * 4;
    esrc[i] = emb + (size_t)row * DDIM + qg * 4;  // + (C0*DDIM + kbase) per step
  }

  float a_r[8];
  #pragma unroll
  for (int i = 0; i < 8; ++i) a_r[i] = arow[R0 + r0 + i];

  float acc[8][8];
  float bd[8];
  int   bki[8];
  #pragma unroll
  for (int i = 0; i < 8; ++i) { bd[i] = 3.4e38f; bki[i] = 0; }

  // ---- prologue: stage step 0 into buf 0 ----
  {
    #pragma unroll
    for (int i = 0; i < 4; ++i)
      gload_lds16(zsrc[i], &zs[0][0][0] + i * 1024 + wid * 256);
    #pragma unroll
    for (int i = 0; i < 4; ++i)
      gload_lds16(esrc[i], &es[0][0][0] + i * 1024 + wid * 256);
  }
  __syncthreads();

  for (int s = 0; s < NSTEPS; ++s) {
    const int buf = s & 1;
    const int kt  = s & 7;

    if (kt == 0) {
      #pragma unroll
      for (int i = 0; i < 8; ++i)
        #pragma unroll
        for (int j = 0; j < 8; ++j) acc[i][j] = 0.0f;
    }

    // ---- issue next-step DMA into the other buffer (before compute) ----
    if (s + 1 < NSTEPS) {
      const int sn = s + 1;
      const int kbase = (sn & 7) * BK;
      const size_t eoff = (size_t)((sn >> 3) * BN) * DDIM + kbase;
      float* zdst = &zs[buf ^ 1][0][0] + wid * 256;
      float* edst = &es[buf ^ 1][0][0] + wid * 256;
      #pragma unroll
      for (int i = 0; i < 4; ++i)
        gload_lds16(zsrc[i] + kbase, zdst + i * 1024);
      #pragma unroll
      for (int i = 0; i < 4; ++i)
        gload_lds16(esrc[i] + eoff, edst + i * 1024);
    }

    // ---- compute: 8 k-groups of 4, 8x8 outer product ----
    #pragma unroll
    for (int c = 0; c < 8; ++c) {
      float4 zr4[8];
      const int zc = (c ^ tyx) * 4;   // swizzled column chunk (same for 8 rows)
      #pragma unroll
      for (int i = 0; i < 8; ++i)
        zr4[i] = *reinterpret_cast<const float4*>(&zs[buf][r0 + i][zc]);
      const int ec = (c ^ txx) * 4;
      #pragma unroll
      for (int j = 0; j < 8; ++j) {
        const float4 ev = *reinterpret_cast<const float4*>(&es[buf][c0 + j][ec]);
        #pragma unroll
        for (int i = 0; i < 8; ++i) {
          acc[i][j] = fmaf(zr4[i].x, ev.x, acc[i][j]);
          acc[i][j] = fmaf(zr4[i].y, ev.y, acc[i][j]);
          acc[i][j] = fmaf(zr4[i].z, ev.z, acc[i][j]);
          acc[i][j] = fmaf(zr4[i].w, ev.w, acc[i][j]);
        }
      }
    }

    // ---- per-chunk argmin epilogue ----
    if (kt == 7) {
      const int C0 = (s >> 3) * BN;
      const float4 cc0 = *reinterpret_cast<const float4*>(cemb + C0 + c0);
      const float4 cc1 = *reinterpret_cast<const float4*>(cemb + C0 + c0 + 4);
      const float cv[8] = {cc0.x, cc0.y, cc0.z, cc0.w,
                           cc1.x, cc1.y, cc1.z, cc1.w};
      #pragma unroll
      for (int i = 0; i < 8; ++i) {
        #pragma unroll
        for (int j = 0; j < 8; ++j) {
          // exact ref chain: fl(a - 2u) (2u exact) then + c
          float t1 = a_r[i] - 2.0f * acc[i][j];
          float d  = t1 + cv[j];
          // strict < keeps first (lowest-k) minimum; k ascends over s,j
          if (d < bd[i]) { bd[i] = d; bki[i] = C0 + c0 + j; }
        }
      }
    }

    __syncthreads();   // drains vmcnt(0): next buffer staged; this buffer free
  }

  // ---- cross-lane argmin over the 16 tx lanes, lexicographic (d, k) ----
  int* bkShared = reinterpret_cast<int*>(&zs[0][0][0]);
  #pragma unroll
  for (int i = 0; i < 8; ++i) {
    float d = bd[i];
    int   k = bki[i];
    #pragma unroll
    for (int off = 1; off < 16; off <<= 1) {
      float od = __shfl_xor(d, off, 64);
      int   ok = __shfl_xor(k, off, 64);
      if (od < d || (od == d && ok < k)) { d = od; k = ok; }
    }
    if (tx == 0) bkShared[r0 + i] = k;
  }
  __syncthreads();

  // ---- gather + z_q_ste write + loss accumulation (coalesced) ----
  float lsum = 0.0f;
  for (int rr = 0; rr < BM; ++rr) {
    const int kb = bkShared[rr];
    const size_t gi = (size_t)(R0 + rr) * DDIM + t;
    const float zv = z[gi];
    const float qv = emb[(size_t)kb * DDIM + t];
    const float diff = qv - zv;            // z_q - z
    out_zq[gi] = zv + diff;                // z + (z_q - z), exact ref chain
    lsum = fmaf(diff, diff, lsum);
  }
  #pragma unroll
  for (int off = 1; off < 64; off <<= 1) lsum += __shfl_xor(lsum, off, 64);
  float* part = reinterpret_cast<float*>(&es[0][0][0]);
  if ((t & 63) == 0) part[wid] = lsum;
  __syncthreads();
  if (t == 0) {
    float tot = (part[0] + part[1]) + (part[2] + part[3]);
    atomicAdd(loss_accum, (double)tot);
  }
  if (t < BM) out_idx[R0 + t] = (float)bkShared[t];
}

// ---------------- scalar losses ----------------------------------------
__global__ void vq_finalize(const double* __restrict__ loss_accum,
                            float* __restrict__ out_losses) {
  double m = *loss_accum / (double)(NROWS * DDIM);
  out_losses[0] = (float)(0.25 * m);   // loss_commit = BETA * mse
  out_losses[1] = (float)m;            // loss_codebook = mse
}

extern "C" void kernel_launch(void* const* d_in, const int* in_sizes, int n_in,
                              void* d_out, int out_size, void* d_ws, size_t ws_size,
                              hipStream_t stream) {
  const float* z   = (const float*)d_in[0];
  const float* emb = (const float*)d_in[1];
  float* out        = (float*)d_out;
  float* out_zq     = out;                            // [8388608]
  float* out_losses = out + (size_t)NROWS * DDIM;     // [2]
  float* out_idx    = out + (size_t)NROWS * DDIM + 2; // [32768] as f32

  double* loss_accum = (double*)d_ws;
  float*  arow = (float*)((char*)d_ws + 256);
  float*  cemb = arow + NROWS;

  hipMemsetAsync(d_ws, 0, 8, stream);                 // zero loss accumulator
  vq_norms<<<(NROWS + NE) / 4, 256, 0, stream>>>(z, emb, arow, cemb);
  vq_main<<<NROWS / BM, 256, 0, stream>>>(z, emb, arow, cemb,
                                          out_zq, out_idx, loss_accum);
  vq_finalize<<<1, 1, 0, stream>>>(loss_accum, out_losses);
}